// Round 1
// baseline (751.366 us; speedup 1.0000x reference)
//
#include <hip/hip_runtime.h>
#include <stdint.h>

#define B_   4
#define T_   1024
#define V_   32000
#define K_   50000
#define N_   (B_*(T_-1))        // 4092 pair-positions
#define TPB  1024
#define U_   49                  // ceil(K_/TPB)
#define KP   (TPB*U_)            // 50176 padded K
#define POS_PER_BLK 16
#define G1   ((N_ + POS_PER_BLK - 1)/POS_PER_BLK)   // 256 blocks = 1/CU (128KB LDS)
#define EPSTGT 1e-8f
#define EPSMOD 1e-12f
#define MAXSLOTS 64

// ---------- helpers ----------
__device__ __forceinline__ uint32_t bf16rne(float x) {
    uint32_t u = __float_as_uint(x);
    u += 0x7FFFu + ((u >> 16) & 1u);
    return u >> 16;
}

// stage one fp32 row of probs into LDS as bf16 (cooperative, vectorized)
__device__ __forceinline__ void stage_row(const float* __restrict__ probs, int r,
                                          ushort* dst, int tid) {
    const float4* src = (const float4*)(probs + (size_t)r * V_);
    for (int i = tid; i < V_ / 4; i += TPB) {
        float4 v = src[i];
        uint2 pk;
        pk.x = bf16rne(v.x) | (bf16rne(v.y) << 16);
        pk.y = bf16rne(v.z) | (bf16rne(v.w) << 16);
        *(uint2*)(dst + i * 4) = pk;
    }
}

// ---------- kernel 0: pack pair indices as bf16-byte-offsets (a*2)<<16 | (b*2) ----------
__global__ void k_pack(const int* __restrict__ pairs, uint32_t* __restrict__ ppk) {
    int k = blockIdx.x * 256 + threadIdx.x;
    if (k >= KP) return;
    uint32_t v = 0;
    if (k < K_) {
        uint32_t a = (uint32_t)pairs[2 * k];
        uint32_t b = (uint32_t)pairs[2 * k + 1];
        v = ((a * 2u) << 16) | (b * 2u);
    }
    ppk[k] = v;
}

// ---------- kernel 0b: n_pairs from mask ----------
__global__ void k_mask(const unsigned char* __restrict__ mask, float* __restrict__ scalars) {
    __shared__ int red[16];
    int tid = threadIdx.x;
    int cnt = 0;
    for (int n = tid; n < N_; n += 1024) {
        int b = n / (T_ - 1);
        int t = n - b * (T_ - 1);
        int r = b * T_ + t;
        cnt += (mask[r] && mask[r + 1]) ? 1 : 0;
    }
    for (int off = 32; off > 0; off >>= 1) cnt += __shfl_down(cnt, off, 64);
    int wid = tid >> 6, lid = tid & 63;
    if (lid == 0) red[wid] = cnt;
    __syncthreads();
    if (tid == 0) {
        int s = 0;
        for (int w = 0; w < 16; ++w) s += red[w];
        scalars[0] = (float)s;
    }
}

// ---------- kernel 1: main gather-accumulate ----------
__global__ __launch_bounds__(TPB) void k_main(
    const float* __restrict__ probs,
    const unsigned char* __restrict__ mask,
    const uint32_t* __restrict__ ppk,
    float* __restrict__ partials, int S)
{
    __shared__ __align__(16) ushort rows[2][V_];   // 128000 B: two bf16 rows (parity slots)
    const int tid = threadIdx.x;
    const int g = blockIdx.x;
    const int n0 = g * POS_PER_BLK;
    const int n1 = min(N_, n0 + POS_PER_BLK);

    float acc[U_];
#pragma unroll
    for (int u = 0; u < U_; ++u) acc[u] = 0.f;

    int staged = -1;   // row index currently staged in slot (staged&1)
    for (int n = n0; n < n1; ++n) {
        const int b = n / (T_ - 1);
        const int t = n - b * (T_ - 1);
        const int r0 = b * T_ + t;
        const int r1 = r0 + 1;

        __syncthreads();                       // previous gathers done before overwrite
        if (staged != r0) stage_row(probs, r0, rows[r0 & 1], tid);
        stage_row(probs, r1, rows[r1 & 1], tid);
        staged = r1;
        __syncthreads();

        if (!(mask[r0] && mask[r1])) continue; // uniform branch (pair_mask)

        const ushort* rp = rows[r0 & 1];
        const ushort* rq = rows[r1 & 1];
        const uint32_t* pp = ppk + tid;
#pragma unroll
        for (int c = 0; c < U_; c += 7) {
            uint32_t pk[7];
#pragma unroll
            for (int j = 0; j < 7; ++j) pk[j] = pp[(c + j) * TPB];
#pragma unroll
            for (int j = 0; j < 7; ++j) {
                uint32_t ao = pk[j] >> 16;          // byte offset of a in bf16 row
                uint32_t bo = pk[j] & 0xFFFFu;      // byte offset of b in bf16 row
                ushort av = *(const ushort*)((const char*)rp + ao);
                ushort bv = *(const ushort*)((const char*)rq + bo);
                float af = __uint_as_float(((uint32_t)av) << 16);
                float bf = __uint_as_float(((uint32_t)bv) << 16);
                acc[c + j] = fmaf(af, bf, acc[c + j]);
            }
        }
    }

    float* slot = partials + (size_t)(g % S) * KP;
#pragma unroll
    for (int u = 0; u < U_; ++u)
        atomicAdd(slot + u * TPB + tid, acc[u]);
}

// ---------- kernel 2: per-k reduce + KL terms ----------
__global__ void k_reduce(const float* __restrict__ partials, const float* __restrict__ tgt,
                         float* __restrict__ scalars, int S) {
    int k = blockIdx.x * 256 + threadIdx.x;
    float n = fmaxf(scalars[0], 1.0f);
    float mt = 0.f, term = 0.f;
    if (k < K_) {
        float ts = 0.f;
        for (int s = 0; s < S; ++s) ts += partials[(size_t)s * KP + k];
        mt = fmaxf(ts / n, EPSMOD);
        float tg = fmaxf(tgt[k], EPSTGT);
        term = mt * (__logf(mt) - __logf(tg));
    }
    for (int off = 32; off > 0; off >>= 1) {
        mt += __shfl_down(mt, off, 64);
        term += __shfl_down(term, off, 64);
    }
    __shared__ float rm[4], rt[4];
    int wid = threadIdx.x >> 6, lid = threadIdx.x & 63;
    if (lid == 0) { rm[wid] = mt; rt[wid] = term; }
    __syncthreads();
    if (threadIdx.x == 0) {
        float sm = 0.f, st = 0.f;
        for (int w = 0; w < 4; ++w) { sm += rm[w]; st += rt[w]; }
        atomicAdd(&scalars[1], sm);   // sum of model_top
        atomicAdd(&scalars[2], st);   // kl_top
    }
}

// ---------- kernel 3: scalar epilogue ----------
__global__ void k_final(const float* __restrict__ scalars, const float* __restrict__ toov,
                        float* __restrict__ out) {
    float S1 = scalars[1], S2 = scalars[2];
    float moov = 1.f - S1;
    moov = fminf(fmaxf(moov, EPSMOD), 1.f - EPSTGT);
    float tv = fmaxf(toov[0], EPSTGT);
    out[0] = S2 + moov * (__logf(moov) - __logf(tv));
}

extern "C" void kernel_launch(void* const* d_in, const int* in_sizes, int n_in,
                              void* d_out, int out_size, void* d_ws, size_t ws_size,
                              hipStream_t stream) {
    const float* probs = (const float*)d_in[0];
    const float* tgt   = (const float*)d_in[1];
    const float* toov  = (const float*)d_in[2];
    const unsigned char* mask = (const unsigned char*)d_in[3];
    const int* pairs   = (const int*)d_in[4];
    float* out = (float*)d_out;

    char* ws = (char*)d_ws;
    uint32_t* ppk = (uint32_t*)ws;                       // KP u32
    size_t off_sc = (size_t)KP * 4;                      // 200704, 256-aligned
    float* scalars = (float*)(ws + off_sc);              // [0]=n_pairs [1]=S1 [2]=S2
    size_t off_pt = off_sc + 256;
    float* partials = (float*)(ws + off_pt);

    long avail = (long)ws_size - (long)off_pt;
    int S = (int)(avail / ((long)KP * 4));
    if (S > MAXSLOTS) S = MAXSLOTS;
    if (S < 1) S = 1;

    hipMemsetAsync(ws + off_sc, 0, 256 + (size_t)S * KP * 4, stream);
    k_pack<<<(KP + 255) / 256, 256, 0, stream>>>(pairs, ppk);
    k_mask<<<1, 1024, 0, stream>>>(mask, scalars);
    k_main<<<G1, TPB, 0, stream>>>(probs, mask, ppk, partials, S);
    k_reduce<<<(K_ + 255) / 256, 256, 0, stream>>>(partials, tgt, scalars, S);
    k_final<<<1, 1, 0, stream>>>(scalars, toov, out);
}

// Round 2
// 747.668 us; speedup vs baseline: 1.0049x; 1.0049x over previous
//
#include <hip/hip_runtime.h>
#include <stdint.h>

#define B_   4
#define T_   1024
#define V_   32000
#define K_   50000
#define N_   (B_*(T_-1))        // 4092 pair-positions
#define TPB  1024
#define U_   49                  // ceil(K_/TPB)
#define KP   (TPB*U_)            // 50176 padded K
#define POS_PER_BLK 16
#define G1   ((N_ + POS_PER_BLK - 1)/POS_PER_BLK)   // 256 blocks = 1/CU (125KB LDS)
#define EPSTGT 1e-8f
#define EPSMOD 1e-12f
#define MAXSLOTS 64
#define W4   (V_/4)              // 8000 float4 per row

// ---------- helpers ----------
__device__ __forceinline__ uint32_t bf16rne(float x) {
    uint32_t u = __float_as_uint(x);
    u += 0x7FFFu + ((u >> 16) & 1u);
    return u >> 16;
}
__device__ __forceinline__ uint2 pack4(float4 v) {
    uint2 pk;
    pk.x = bf16rne(v.x) | (bf16rne(v.y) << 16);
    pk.y = bf16rne(v.z) | (bf16rne(v.w) << 16);
    return pk;
}

// synchronous stage: fp32 global row -> bf16 LDS row
__device__ __forceinline__ void stage_row(const float* __restrict__ probs, int r,
                                          ushort* dst, int tid) {
    const float4* src = (const float4*)(probs + (size_t)r * V_);
    for (int i = tid; i < W4; i += TPB) {
        *(uint2*)(dst + i * 4) = pack4(src[i]);
    }
}

// ---------- kernel 0: pack pair indices as bf16-byte-offsets (a*2)<<16 | (b*2) ----------
__global__ void k_pack(const int* __restrict__ pairs, uint32_t* __restrict__ ppk) {
    int k = blockIdx.x * 256 + threadIdx.x;
    if (k >= KP) return;
    uint32_t v = 0;
    if (k < K_) {
        uint32_t a = (uint32_t)pairs[2 * k];
        uint32_t b = (uint32_t)pairs[2 * k + 1];
        v = ((a * 2u) << 16) | (b * 2u);
    }
    ppk[k] = v;
}

// ---------- kernel 0b: n_pairs from mask ----------
__global__ void k_mask(const unsigned char* __restrict__ mask, float* __restrict__ scalars) {
    __shared__ int red[16];
    int tid = threadIdx.x;
    int cnt = 0;
    for (int n = tid; n < N_; n += 1024) {
        int b = n / (T_ - 1);
        int t = n - b * (T_ - 1);
        int r = b * T_ + t;
        cnt += (mask[r] && mask[r + 1]) ? 1 : 0;
    }
    for (int off = 32; off > 0; off >>= 1) cnt += __shfl_down(cnt, off, 64);
    int wid = tid >> 6, lid = tid & 63;
    if (lid == 0) red[wid] = cnt;
    __syncthreads();
    if (tid == 0) {
        int s = 0;
        for (int w = 0; w < 16; ++w) s += red[w];
        scalars[0] = (float)s;
    }
}

// ---------- kernel 1: main gather-accumulate (register-pipelined staging) ----------
__global__ __launch_bounds__(TPB) void k_main(
    const float* __restrict__ probs,
    const unsigned char* __restrict__ mask,
    const uint32_t* __restrict__ ppk,
    float* __restrict__ partials, int S)
{
    __shared__ __align__(16) ushort rows[2][V_];   // 125 KB: two bf16 rows (parity slots)
    const int tid = threadIdx.x;
    const int g = blockIdx.x;
    const int n0 = g * POS_PER_BLK;
    const int n1 = min(N_, n0 + POS_PER_BLK);

    float acc[U_];
#pragma unroll
    for (int u = 0; u < U_; ++u) acc[u] = 0.f;

    // row0(n) = n + n/(T-1); rows for position n are (r0, r0+1)
    int r0 = n0 + n0 / (T_ - 1);
    int r1 = r0 + 1;
    stage_row(probs, r0, rows[r0 & 1], tid);
    stage_row(probs, r1, rows[r1 & 1], tid);

    for (int n = n0; n < n1; ++n) {
        // decide prefetch for next position
        const int nn = n + 1;
        const bool more = (nn < n1);
        const int nr0 = nn + nn / (T_ - 1);   // valid even when !more (unused)
        const int nr1 = nr0 + 1;
        // normal: nr0==r1 -> prefetch nr1 (lands in slot r0&1)
        // batch boundary: nr0==r1+1 -> prefetch nr0 (also slot r0&1), sync-stage nr1 after
        const int pre_row = more ? ((nr0 == r1) ? nr1 : nr0) : -1;
        const bool extra = more && (nr0 != r1);

        // [A] issue global loads, half 0 (j=0..3; i <= 4095 < 8000, no guard)
        const float4* src = (const float4*)(probs + (size_t)((pre_row >= 0) ? pre_row : 0) * V_);
        float4 L0[4];
#pragma unroll
        for (int j = 0; j < 4; ++j) L0[j] = src[tid + j * TPB];

        __syncthreads();     // staged rows (prev iter / initial) now visible

        const bool active = mask[r0] && mask[r1];   // block-uniform
        const ushort* rp = rows[r0 & 1];
        const ushort* rq = rows[r1 & 1];
        const uint32_t* pp = ppk + tid;

        // [B] gather chunks 0..3 (28 pairs)
        if (active) {
#pragma unroll
            for (int c = 0; c < 28; c += 7) {
                uint32_t pk[7];
#pragma unroll
                for (int j = 0; j < 7; ++j) pk[j] = pp[(c + j) * TPB];
#pragma unroll
                for (int j = 0; j < 7; ++j) {
                    uint32_t ao = pk[j] >> 16;
                    uint32_t bo = pk[j] & 0xFFFFu;
                    ushort av = *(const ushort*)((const char*)rp + ao);
                    ushort bv = *(const ushort*)((const char*)rq + bo);
                    float af = __uint_as_float(((uint32_t)av) << 16);
                    float bf = __uint_as_float(((uint32_t)bv) << 16);
                    acc[c + j] = fmaf(af, bf, acc[c + j]);
                }
            }
        }

        // [C] pack half 0; issue loads half 1 (j=3 needs tail clamp: i<8000)
        uint2 P0[4];
#pragma unroll
        for (int j = 0; j < 4; ++j) P0[j] = pack4(L0[j]);
        float4 L1[4];
#pragma unroll
        for (int j = 0; j < 4; ++j) {
            int i = tid + (4 + j) * TPB;
            int ic = (i < W4) ? i : 0;          // clamp to stay in-bounds
            L1[j] = src[ic];
        }

        // [D] gather chunks 4..6 (21 pairs)
        if (active) {
#pragma unroll
            for (int c = 28; c < U_; c += 7) {
                uint32_t pk[7];
#pragma unroll
                for (int j = 0; j < 7; ++j) pk[j] = pp[(c + j) * TPB];
#pragma unroll
                for (int j = 0; j < 7; ++j) {
                    uint32_t ao = pk[j] >> 16;
                    uint32_t bo = pk[j] & 0xFFFFu;
                    ushort av = *(const ushort*)((const char*)rp + ao);
                    ushort bv = *(const ushort*)((const char*)rq + bo);
                    float af = __uint_as_float(((uint32_t)av) << 16);
                    float bf = __uint_as_float(((uint32_t)bv) << 16);
                    acc[c + j] = fmaf(af, bf, acc[c + j]);
                }
            }
        }

        __syncthreads();     // [E] all gathers for position n done

        // [F] commit prefetched row to LDS (slot r0&1, now free)
        if (pre_row >= 0) {
            ushort* dst = rows[pre_row & 1];
#pragma unroll
            for (int j = 0; j < 4; ++j) {
                int i = tid + j * TPB;
                *(uint2*)(dst + i * 4) = P0[j];
            }
#pragma unroll
            for (int j = 0; j < 4; ++j) {
                int i = tid + (4 + j) * TPB;
                if (i < W4) *(uint2*)(dst + i * 4) = pack4(L1[j]);
            }
            if (extra) stage_row(probs, nr1, rows[nr1 & 1], tid);  // 3 blocks, once
        }

        r0 = nr0; r1 = nr1;
    }

    float* slot = partials + (size_t)(g % S) * KP;
#pragma unroll
    for (int u = 0; u < U_; ++u)
        atomicAdd(slot + u * TPB + tid, acc[u]);
}

// ---------- kernel 2: per-k reduce + KL terms ----------
__global__ void k_reduce(const float* __restrict__ partials, const float* __restrict__ tgt,
                         float* __restrict__ scalars, int S) {
    int k = blockIdx.x * 256 + threadIdx.x;
    float n = fmaxf(scalars[0], 1.0f);
    float mt = 0.f, term = 0.f;
    if (k < K_) {
        float ts = 0.f;
        for (int s = 0; s < S; ++s) ts += partials[(size_t)s * KP + k];
        mt = fmaxf(ts / n, EPSMOD);
        float tg = fmaxf(tgt[k], EPSTGT);
        term = mt * (__logf(mt) - __logf(tg));
    }
    for (int off = 32; off > 0; off >>= 1) {
        mt += __shfl_down(mt, off, 64);
        term += __shfl_down(term, off, 64);
    }
    __shared__ float rm[4], rt[4];
    int wid = threadIdx.x >> 6, lid = threadIdx.x & 63;
    if (lid == 0) { rm[wid] = mt; rt[wid] = term; }
    __syncthreads();
    if (threadIdx.x == 0) {
        float sm = 0.f, st = 0.f;
        for (int w = 0; w < 4; ++w) { sm += rm[w]; st += rt[w]; }
        atomicAdd(&scalars[1], sm);   // sum of model_top
        atomicAdd(&scalars[2], st);   // kl_top
    }
}

// ---------- kernel 3: scalar epilogue ----------
__global__ void k_final(const float* __restrict__ scalars, const float* __restrict__ toov,
                        float* __restrict__ out) {
    float S1 = scalars[1], S2 = scalars[2];
    float moov = 1.f - S1;
    moov = fminf(fmaxf(moov, EPSMOD), 1.f - EPSTGT);
    float tv = fmaxf(toov[0], EPSTGT);
    out[0] = S2 + moov * (__logf(moov) - __logf(tv));
}

extern "C" void kernel_launch(void* const* d_in, const int* in_sizes, int n_in,
                              void* d_out, int out_size, void* d_ws, size_t ws_size,
                              hipStream_t stream) {
    const float* probs = (const float*)d_in[0];
    const float* tgt   = (const float*)d_in[1];
    const float* toov  = (const float*)d_in[2];
    const unsigned char* mask = (const unsigned char*)d_in[3];
    const int* pairs   = (const int*)d_in[4];
    float* out = (float*)d_out;

    char* ws = (char*)d_ws;
    uint32_t* ppk = (uint32_t*)ws;                       // KP u32
    size_t off_sc = (size_t)KP * 4;                      // 200704, 256-aligned
    float* scalars = (float*)(ws + off_sc);              // [0]=n_pairs [1]=S1 [2]=S2
    size_t off_pt = off_sc + 256;
    float* partials = (float*)(ws + off_pt);

    long avail = (long)ws_size - (long)off_pt;
    int S = (int)(avail / ((long)KP * 4));
    if (S > MAXSLOTS) S = MAXSLOTS;
    if (S < 1) S = 1;

    hipMemsetAsync(ws + off_sc, 0, 256 + (size_t)S * KP * 4, stream);
    k_pack<<<(KP + 255) / 256, 256, 0, stream>>>(pairs, ppk);
    k_mask<<<1, 1024, 0, stream>>>(mask, scalars);
    k_main<<<G1, TPB, 0, stream>>>(probs, mask, ppk, partials, S);
    k_reduce<<<(K_ + 255) / 256, 256, 0, stream>>>(partials, tgt, scalars, S);
    k_final<<<1, 1, 0, stream>>>(scalars, toov, out);
}

// Round 3
// 735.436 us; speedup vs baseline: 1.0217x; 1.0166x over previous
//
#include <hip/hip_runtime.h>
#include <stdint.h>

#define B_   4
#define T_   1024
#define V_   32000
#define K_   50000
#define N_   (B_*(T_-1))        // 4092 pair-positions
#define TPB  1024
#define U_   49                  // ceil(K_/TPB)
#define KP   (TPB*U_)            // 50176 padded K
#define POS_PER_BLK 16
#define G1   ((N_ + POS_PER_BLK - 1)/POS_PER_BLK)   // 256 blocks = 1/CU (125KB LDS)
#define EPSTGT 1e-8f
#define EPSMOD 1e-12f
#define W4   (V_/4)              // 8000 float4 per row

// ---------- helpers ----------
__device__ __forceinline__ uint32_t bf16rne(float x) {
    uint32_t u = __float_as_uint(x);
    u += 0x7FFFu + ((u >> 16) & 1u);
    return u >> 16;
}
__device__ __forceinline__ uint2 pack4(float4 v) {
    uint2 pk;
    pk.x = bf16rne(v.x) | (bf16rne(v.y) << 16);
    pk.y = bf16rne(v.z) | (bf16rne(v.w) << 16);
    return pk;
}
// synchronous stage: fp32 global row -> bf16 LDS row (prologue / batch-boundary only)
__device__ __forceinline__ void stage_row(const float* __restrict__ probs, int r,
                                          ushort* dst, int tid) {
    const float4* src = (const float4*)(probs + (size_t)r * V_);
    for (int i = tid; i < W4; i += TPB) {
        *(uint2*)(dst + i * 4) = pack4(src[i]);
    }
}

// gather one pair: 2 LDS bf16 reads + fma
#define GATHER(pkv, accv) do {                                          \
    uint32_t ao_ = (pkv) >> 16, bo_ = (pkv) & 0xFFFFu;                  \
    ushort av_ = *(const ushort*)(rp + ao_);                            \
    ushort bv_ = *(const ushort*)(rq + bo_);                            \
    accv = fmaf(__uint_as_float((uint32_t)av_ << 16),                   \
                __uint_as_float((uint32_t)bv_ << 16), accv);            \
} while (0)

// ---------- kernel 0: pack pair indices as bf16-byte-offsets (a*2)<<16 | (b*2) ----------
__global__ void k_pack(const int* __restrict__ pairs, uint32_t* __restrict__ ppk) {
    int k = blockIdx.x * 256 + threadIdx.x;
    if (k >= KP) return;
    uint32_t v = 0;
    if (k < K_) {
        uint32_t a = (uint32_t)pairs[2 * k];
        uint32_t b = (uint32_t)pairs[2 * k + 1];
        v = ((a * 2u) << 16) | (b * 2u);
    }
    ppk[k] = v;
}

// ---------- kernel 0b: n_pairs from mask ----------
__global__ void k_mask(const unsigned char* __restrict__ mask, float* __restrict__ scalars) {
    __shared__ int red[16];
    int tid = threadIdx.x;
    int cnt = 0;
    for (int n = tid; n < N_; n += 1024) {
        int b = n / (T_ - 1);
        int t = n - b * (T_ - 1);
        int r = b * T_ + t;
        cnt += (mask[r] && mask[r + 1]) ? 1 : 0;
    }
    for (int off = 32; off > 0; off >>= 1) cnt += __shfl_down(cnt, off, 64);
    int wid = tid >> 6, lid = tid & 63;
    if (lid == 0) red[wid] = cnt;
    __syncthreads();
    if (tid == 0) {
        int s = 0;
        for (int w = 0; w < 16; ++w) s += red[w];
        scalars[0] = (float)s;
    }
}

// ---------- kernel 1: main gather-accumulate ----------
// Pipeline per position: barrier1 -> issue pkA,L0 -> gather(0..13) -> issue pkB
// -> gather(14..27) -> pack L0, issue L1 -> gather(28..48) -> barrier2 -> commit.
// FIFO vmcnt discipline: every wait targets loads OLDER than anything still wanted
// in flight, so row prefetch stays outstanding through the whole gather phase.
__global__ __launch_bounds__(TPB) void k_main(
    const float* __restrict__ probs,
    const unsigned char* __restrict__ mask,
    const uint32_t* __restrict__ ppk,
    float* __restrict__ partials, int S, int direct)
{
    __shared__ __align__(16) ushort rows[2][V_];   // 125 KB: two bf16 rows (parity slots)
    __shared__ unsigned char mask_s[32];
    const int tid = threadIdx.x;
    const int g = blockIdx.x;
    const int n0 = g * POS_PER_BLK;
    const int n1 = min(N_, n0 + POS_PER_BLK);

    int r0 = n0 + n0 / (T_ - 1);     // row0(n) = n + n/(T-1)
    int r1 = r0 + 1;
    const int rbase = r0;
    {
        int rlast = (n1 - 1) + (n1 - 1) / (T_ - 1) + 1;
        int nrows = rlast - rbase + 1;            // <= 18
        if (tid < nrows) mask_s[tid] = mask[rbase + tid];
    }

    float acc[U_];
#pragma unroll
    for (int u = 0; u < U_; ++u) acc[u] = 0.f;

    stage_row(probs, r0, rows[r0 & 1], tid);
    stage_row(probs, r1, rows[r1 & 1], tid);

    const uint32_t* pp = ppk + tid;

    for (int n = n0; n < n1; ++n) {
        const int nn = n + 1;
        const bool more = (nn < n1);
        const int nr0 = nn + nn / (T_ - 1);
        const int nr1 = nr0 + 1;
        // normal: nr0==r1 -> prefetch nr1; batch boundary: prefetch nr0, sync-stage nr1
        const int pre_row = more ? ((nr0 == r1) ? nr1 : nr0) : -1;
        const bool extra = more && (nr0 != r1);
        const int ld_row = (pre_row >= 0) ? pre_row : 0;
        const float4* src = (const float4*)(probs + (size_t)ld_row * V_);

        __syncthreads();                           // barrier1: staged rows visible

        // [1] issue pair-index loads, chunks 0..3 (oldest in vmcnt FIFO)
        uint32_t pkA[28];
#pragma unroll
        for (int j = 0; j < 28; ++j) pkA[j] = pp[j * TPB];
        __builtin_amdgcn_sched_barrier(0);
        // [2] issue row prefetch, half 0 (stays in flight through gathers)
        float4 L0[4];
#pragma unroll
        for (int j = 0; j < 4; ++j) L0[j] = src[tid + j * TPB];
        __builtin_amdgcn_sched_barrier(0);

        const bool active = mask_s[r0 - rbase] && mask_s[r1 - rbase];
        const char* rp = (const char*)rows[r0 & 1];
        const char* rq = (const char*)rows[r1 & 1];

        // [3] gather pairs 0..13 (waits only pkA prefix)
        if (active) {
#pragma unroll
            for (int j = 0; j < 14; ++j) GATHER(pkA[j], acc[j]);
        }
        // [4] issue pair-index loads, chunks 4..6 (younger than L0)
        uint32_t pkB[21];
#pragma unroll
        for (int j = 0; j < 21; ++j) pkB[j] = pp[(28 + j) * TPB];
        __builtin_amdgcn_sched_barrier(0);
        // [5] gather pairs 14..27
        if (active) {
#pragma unroll
            for (int j = 14; j < 28; ++j) GATHER(pkA[j], acc[j]);
        }
        // [6] pack half 0 (waits L0; pkB is younger -> untouched)
        uint2 P0[4];
#pragma unroll
        for (int j = 0; j < 4; ++j) P0[j] = pack4(L0[j]);
        // [7] issue row prefetch, half 1 (youngest)
        float4 L1[4];
#pragma unroll
        for (int j = 0; j < 4; ++j) {
            int i = tid + (4 + j) * TPB;
            L1[j] = src[(i < W4) ? i : 0];
        }
        __builtin_amdgcn_sched_barrier(0);
        // [8] gather pairs 28..48 (waits pkB; L1 younger -> stays in flight)
        if (active) {
#pragma unroll
            for (int j = 0; j < 21; ++j) GATHER(pkB[j], acc[28 + j]);
        }

        __syncthreads();                           // barrier2: gathers done; L1 ~done

        // [9] commit prefetched row into freed slot
        if (pre_row >= 0) {
            ushort* dst = rows[pre_row & 1];
#pragma unroll
            for (int j = 0; j < 4; ++j)
                *(uint2*)(dst + (tid + j * TPB) * 4) = P0[j];
#pragma unroll
            for (int j = 0; j < 4; ++j) {
                int i = tid + (4 + j) * TPB;
                if (i < W4) *(uint2*)(dst + i * 4) = pack4(L1[j]);
            }
            if (extra) stage_row(probs, nr1, rows[nr1 & 1], tid);  // 3 blocks, once
        }
        r0 = nr0; r1 = nr1;
    }

    if (direct) {       // private slot per block: plain coalesced stores, no atomics
        float* slot = partials + (size_t)g * KP;
#pragma unroll
        for (int u = 0; u < U_; ++u) slot[u * TPB + tid] = acc[u];
    } else {
        float* slot = partials + (size_t)(g % S) * KP;
#pragma unroll
        for (int u = 0; u < U_; ++u) atomicAdd(slot + u * TPB + tid, acc[u]);
    }
}

// ---------- kernel 2: per-k reduce + KL terms ----------
__global__ void k_reduce(const float* __restrict__ partials, const float* __restrict__ tgt,
                         float* __restrict__ scalars, int S) {
    int k = blockIdx.x * 256 + threadIdx.x;
    float n = fmaxf(scalars[0], 1.0f);
    float mt = 0.f, term = 0.f;
    if (k < K_) {
        float ts = 0.f;
        for (int s = 0; s < S; ++s) ts += partials[(size_t)s * KP + k];
        mt = fmaxf(ts / n, EPSMOD);
        float tg = fmaxf(tgt[k], EPSTGT);
        term = mt * (__logf(mt) - __logf(tg));
    }
    for (int off = 32; off > 0; off >>= 1) {
        mt += __shfl_down(mt, off, 64);
        term += __shfl_down(term, off, 64);
    }
    __shared__ float rm[4], rt[4];
    int wid = threadIdx.x >> 6, lid = threadIdx.x & 63;
    if (lid == 0) { rm[wid] = mt; rt[wid] = term; }
    __syncthreads();
    if (threadIdx.x == 0) {
        float sm = 0.f, st = 0.f;
        for (int w = 0; w < 4; ++w) { sm += rm[w]; st += rt[w]; }
        atomicAdd(&scalars[1], sm);   // sum of model_top
        atomicAdd(&scalars[2], st);   // kl_top
    }
}

// ---------- kernel 3: scalar epilogue ----------
__global__ void k_final(const float* __restrict__ scalars, const float* __restrict__ toov,
                        float* __restrict__ out) {
    float S1 = scalars[1], S2 = scalars[2];
    float moov = 1.f - S1;
    moov = fminf(fmaxf(moov, EPSMOD), 1.f - EPSTGT);
    float tv = fmaxf(toov[0], EPSTGT);
    out[0] = S2 + moov * (__logf(moov) - __logf(tv));
}

extern "C" void kernel_launch(void* const* d_in, const int* in_sizes, int n_in,
                              void* d_out, int out_size, void* d_ws, size_t ws_size,
                              hipStream_t stream) {
    const float* probs = (const float*)d_in[0];
    const float* tgt   = (const float*)d_in[1];
    const float* toov  = (const float*)d_in[2];
    const unsigned char* mask = (const unsigned char*)d_in[3];
    const int* pairs   = (const int*)d_in[4];
    float* out = (float*)d_out;

    char* ws = (char*)d_ws;
    uint32_t* ppk = (uint32_t*)ws;                       // KP u32
    size_t off_sc = (size_t)KP * 4;                      // 200704, 256-aligned
    float* scalars = (float*)(ws + off_sc);              // [0]=n_pairs [1]=S1 [2]=S2
    size_t off_pt = off_sc + 256;
    float* partials = (float*)(ws + off_pt);

    long avail = (long)ws_size - (long)off_pt;
    int smax = (int)(avail / ((long)KP * 4));
    int direct = (smax >= G1) ? 1 : 0;
    int S = direct ? G1 : (smax < 1 ? 1 : (smax > 64 ? 64 : smax));

    // scalars always zeroed; partials only when accumulated via atomics
    hipMemsetAsync(ws + off_sc, 0, 256, stream);
    if (!direct) hipMemsetAsync(partials, 0, (size_t)S * KP * 4, stream);
    k_pack<<<(KP + 255) / 256, 256, 0, stream>>>(pairs, ppk);
    k_mask<<<1, 1024, 0, stream>>>(mask, scalars);
    k_main<<<G1, TPB, 0, stream>>>(probs, mask, ppk, partials, S, direct);
    k_reduce<<<(K_ + 255) / 256, 256, 0, stream>>>(partials, tgt, scalars, S);
    k_final<<<1, 1, 0, stream>>>(scalars, toov, out);
}